// Round 7
// baseline (667.631 us; speedup 1.0000x reference)
//
#include <hip/hip_runtime.h>
#include <math.h>

typedef short bf8 __attribute__((ext_vector_type(8)));   // 8 bf16 in 4 VGPRs
typedef float f4 __attribute__((ext_vector_type(4)));
typedef unsigned short ushort_t;

#define BRANGE 128  // nodes per bucket (dst>>7)

// ---------------- helpers ----------------
__device__ __forceinline__ float lanebcast(float v, int l) {
  return __int_as_float(__builtin_amdgcn_readlane(__float_as_int(v), l));
}
__device__ __forceinline__ int ilanebcast(int v, int l) {
  return __builtin_amdgcn_readlane(v, l);
}

__device__ __forceinline__ float wave_sum(float v) {
#pragma unroll
  for (int off = 32; off > 0; off >>= 1) v += __shfl_xor(v, off, 64);
  return v;
}

__device__ __forceinline__ ushort_t f2bf(float x) {  // RNE fp32->bf16 bits
  unsigned int u = __float_as_uint(x);
  return (ushort_t)((u + 0x7fffu + ((u >> 16) & 1u)) >> 16);
}
__device__ __forceinline__ float b2f(ushort_t h) {
  return __uint_as_float(((unsigned int)h) << 16);
}

// ================= bucketed CSR build =================
// Phase 1: histogram of dst buckets (LDS-aggregated)
__global__ __launch_bounds__(256) void k_ehist(const int* __restrict__ dst,
                                               int* __restrict__ bcnt, int E, int nbuk) {
  __shared__ int h[512];
  int tid = threadIdx.x;
  for (int i = tid; i < nbuk; i += 256) h[i] = 0;
  __syncthreads();
  int stride = gridDim.x * 256;
  for (int e = blockIdx.x * 256 + tid; e < E; e += stride)
    atomicAdd(&h[dst[e] >> 7], 1);
  __syncthreads();
  for (int i = tid; i < nbuk; i += 256)
    if (h[i]) atomicAdd(&bcnt[i], h[i]);
}

// Phase 2: spine scan of bucket counts (nbuk <= 512)
__global__ __launch_bounds__(512) void k_espine(const int* __restrict__ bcnt,
                                                int* __restrict__ edgebase,
                                                int* __restrict__ gcursor, int nbuk,
                                                int* __restrict__ rowstart, int n, int E) {
  __shared__ int smem[512];
  int tid = threadIdx.x;
  int v = (tid < nbuk) ? bcnt[tid] : 0;
  smem[tid] = v;
  __syncthreads();
  for (int off = 1; off < 512; off <<= 1) {
    int t = (tid >= off) ? smem[tid - off] : 0;
    __syncthreads();
    smem[tid] += t;
    __syncthreads();
  }
  if (tid < nbuk) {
    int ex = smem[tid] - v;
    edgebase[tid] = ex;
    gcursor[tid] = ex;
  }
  if (tid == 0) rowstart[n] = E + n;
}

// Phase 3: scatter packed edges into bucket-sequential regions
__global__ __launch_bounds__(256) void k_ebucket(const int* __restrict__ es,
                                                 const int* __restrict__ ed,
                                                 int* __restrict__ gcursor,
                                                 int* __restrict__ bedges, int E) {
  int i = blockIdx.x * 256 + threadIdx.x;
  int stride = gridDim.x * 256;
  for (int e = i; e < E; e += stride) {
    int s = es[e], d = ed[e];
    int pos = atomicAdd(&gcursor[d >> 7], 1);
    bedges[pos] = (s << 7) | (d & 127);
  }
}

// Phase 4: per-bucket counting sort -> colidx, rowstart, dinv (self-loops added)
__global__ __launch_bounds__(256) void k_ebsort(
    const int* __restrict__ bedges, const int* __restrict__ edgebase,
    const int* __restrict__ bcnt, int* __restrict__ colidx,
    int* __restrict__ rowstart, float* __restrict__ dinv, int n) {
  __shared__ int h[128];
  __shared__ int c[128];
  int b = blockIdx.x, tid = threadIdx.x;
  int nodes0 = b * BRANGE;
  int nnode = min(BRANGE, n - nodes0);
  int ebase = edgebase[b], ecnt = bcnt[b];
  int colbase = ebase + nodes0;  // prior buckets contribute edges + their self-loops
  if (tid < 128) h[tid] = (tid < nnode) ? 1 : 0;  // self-loop
  __syncthreads();
  for (int k = ebase + tid; k < ebase + ecnt; k += 256)
    atomicAdd(&h[bedges[k] & 127], 1);
  __syncthreads();
  int own = (tid < 128) ? h[tid] : 0;  // = deg (incl self-loop)
  for (int off = 1; off < 128; off <<= 1) {
    int t = (tid >= off && tid < 128) ? h[tid - off] : 0;
    __syncthreads();
    if (tid < 128) h[tid] += t;
    __syncthreads();
  }
  if (tid < nnode) {
    int excl = h[tid] - own;
    int node = nodes0 + tid;
    rowstart[node] = colbase + excl;
    dinv[node] = 1.0f / sqrtf((float)own);
    colidx[colbase + excl] = node;  // self-loop first
    c[tid] = excl + 1;
  }
  __syncthreads();
  for (int k = ebase + tid; k < ebase + ecnt; k += 256) {
    int p = bedges[k];
    int pos = atomicAdd(&c[p & 127], 1);
    colidx[colbase + pos] = p >> 7;
  }
}

// ---------------- weight swizzle into MFMA B-fragment layout ----------------
// B-frag for 16x16x32: lane holds B[k=(lane>>4)*8+j][n=lane&15], j=0..7.

// W0 [128,64]
__global__ void k_wswz0(const float* __restrict__ W, ushort_t* __restrict__ Bh,
                        ushort_t* __restrict__ Bl) {
  for (int e = threadIdx.x; e < 4 * 4 * 64; e += 256) {
    int lane = e & 63, kc = (e >> 6) & 3, ct = e >> 8;
    int k0 = kc * 32 + (lane >> 4) * 8;
    int col = ct * 16 + (lane & 15);
#pragma unroll
    for (int j = 0; j < 8; j++) {
      float w = W[(k0 + j) * 64 + col];
      ushort_t h = f2bf(w);
      Bh[(size_t)e * 8 + j] = h;
      Bl[(size_t)e * 8 + j] = f2bf(w - b2f(h));
    }
  }
}

// Wg_cat [256,64]: Wcat[k=h*64+c][col] = gat_w[c*256 + h*64 + col]
__global__ void k_wswzg(const float* __restrict__ W, ushort_t* __restrict__ Bh,
                        ushort_t* __restrict__ Bl) {
  for (int e = threadIdx.x; e < 4 * 8 * 64; e += 256) {
    int lane = e & 63, kc = (e >> 6) & 7, ct = e >> 9;
    int k0 = kc * 32 + (lane >> 4) * 8;
    int col = ct * 16 + (lane & 15);
#pragma unroll
    for (int j = 0; j < 8; j++) {
      int k = k0 + j;
      float w = W[(k & 63) * 256 + (k >> 6) * 64 + col];
      ushort_t h = f2bf(w);
      Bh[(size_t)e * 8 + j] = h;
      Bl[(size_t)e * 8 + j] = f2bf(w - b2f(h));
    }
  }
}

// ---------------- K1: H0'[N,64] = bf16(dinv[n] * (X[N,128] @ W0)) via MFMA --
__global__ __launch_bounds__(256) void k_gemm0_mfma(
    const float* __restrict__ X, const ushort_t* __restrict__ Bh,
    const ushort_t* __restrict__ Bl, const float* __restrict__ dinv,
    ushort_t* __restrict__ H, int n, int ntiles) {
  int tid = threadIdx.x, lane = tid & 63, wave = tid >> 6;
  int m = lane & 15, q = lane >> 4;
  for (int tile = blockIdx.x * 4 + wave; tile < ntiles; tile += gridDim.x * 4) {
    int ra = tile * 16 + m;
    if (ra >= n) ra = n - 1;
    const float* xrow = X + (size_t)ra * 128;
    f4 acc[4];
#pragma unroll
    for (int ct = 0; ct < 4; ct++) acc[ct] = (f4){0.f, 0.f, 0.f, 0.f};
#pragma unroll 2
    for (int kc = 0; kc < 4; kc++) {
      int ko = kc * 32 + q * 8;
      float4 xa = *(const float4*)(xrow + ko);
      float4 xb = *(const float4*)(xrow + ko + 4);
      float f[8] = {xa.x, xa.y, xa.z, xa.w, xb.x, xb.y, xb.z, xb.w};
      union { ushort_t u[8]; bf8 v; } Uh, Ul;
#pragma unroll
      for (int j = 0; j < 8; j++) {
        ushort_t h = f2bf(f[j]);
        Uh.u[j] = h;
        Ul.u[j] = f2bf(f[j] - b2f(h));
      }
#pragma unroll
      for (int ct = 0; ct < 4; ct++) {
        size_t boff = ((size_t)(ct * 4 + kc) * 64 + lane) * 8;
        bf8 bh = *(const bf8*)(Bh + boff);
        bf8 bl = *(const bf8*)(Bl + boff);
        acc[ct] = __builtin_amdgcn_mfma_f32_16x16x32_bf16(Uh.v, bh, acc[ct], 0, 0, 0);
        acc[ct] = __builtin_amdgcn_mfma_f32_16x16x32_bf16(Ul.v, bh, acc[ct], 0, 0, 0);
        acc[ct] = __builtin_amdgcn_mfma_f32_16x16x32_bf16(Uh.v, bl, acc[ct], 0, 0, 0);
      }
    }
#pragma unroll
    for (int r = 0; r < 4; r++) {
      int row = tile * 16 + q * 4 + r;
      if (row < n) {
        float dv = dinv[row];
#pragma unroll
        for (int ct = 0; ct < 4; ct++)
          H[(size_t)row * 64 + ct * 16 + m] = f2bf(acc[ct][r] * dv);
      }
    }
  }
}

// ---------------- gather core (bf16 rows) ----------------
__device__ __forceinline__ float gather_sum(const ushort_t* __restrict__ h_in,
                                            const int* __restrict__ colidx,
                                            int s0, int s1, int lane) {
  float acc = 0.0f, accB = 0.0f;
  for (int base = s0; base < s1; base += 64) {
    int cnt = min(64, s1 - base);
    int myidx = (lane < cnt) ? colidx[base + lane] : 0;
    int k = 0;
    for (; k + 3 < cnt; k += 4) {
      int sa = ilanebcast(myidx, k);
      int sb = ilanebcast(myidx, k + 1);
      int sc = ilanebcast(myidx, k + 2);
      int sd = ilanebcast(myidx, k + 3);
      float va = b2f(h_in[(size_t)sa * 64 + lane]);
      float vb = b2f(h_in[(size_t)sb * 64 + lane]);
      float vc = b2f(h_in[(size_t)sc * 64 + lane]);
      float vd = b2f(h_in[(size_t)sd * 64 + lane]);
      acc += va; accB += vb; acc += vc; accB += vd;
    }
    for (; k < cnt; k++) {
      int sa = ilanebcast(myidx, k);
      acc += b2f(h_in[(size_t)sa * 64 + lane]);
    }
  }
  return acc + accB;
}

// ---------------- K2/K3: fused GCN agg + next GEMM (readlane GEMV) --------
__global__ __launch_bounds__(256) void k_agg_gemm(
    const ushort_t* __restrict__ h_in, const float* __restrict__ dinv,
    const int* __restrict__ rowstart, const int* __restrict__ colidx,
    const float* __restrict__ bias, const float* __restrict__ Wn,
    ushort_t* __restrict__ h_out, int n) {
  __shared__ float lds_w[64 * 64];
  int tid = threadIdx.x;
  for (int idx = tid; idx < 64 * 64; idx += 256) lds_w[idx] = Wn[idx];
  __syncthreads();
  int lane = tid & 63;
  float bv = bias[lane];
  int gw = blockIdx.x * 4 + (tid >> 6);
  int nw = gridDim.x * 4;
  for (int node = gw; node < n; node += nw) {
    int s0 = rowstart[node], s1 = rowstart[node + 1];
    float acc = gather_sum(h_in, colidx, s0, s1, lane);
    float dvn = dinv[node];
    float x1 = fmaxf(fmaf(dvn, acc, bv), 0.0f);
    float o = 0.0f;
#pragma unroll 8
    for (int k = 0; k < 64; k++)
      o = fmaf(lanebcast(x1, k), lds_w[k * 64 + lane], o);
    h_out[(size_t)node * 64 + lane] = f2bf(o * dvn);
  }
}

// ---------------- K4: GCN layer-2 agg + GAT attention logits ----------------
__global__ __launch_bounds__(256) void k_agg_gatpre(
    const ushort_t* __restrict__ h_in, const float* __restrict__ dinv,
    const int* __restrict__ rowstart, const int* __restrict__ colidx,
    const float* __restrict__ bias,
    const float* __restrict__ q_src, const float* __restrict__ q_dst,
    ushort_t* __restrict__ x3, float* __restrict__ a_src, float* __restrict__ a_dst,
    int n) {
  int tid = threadIdx.x;
  int lane = tid & 63;
  float bv = bias[lane];
  float qs[4], qd[4];
#pragma unroll
  for (int h = 0; h < 4; h++) {
    qs[h] = q_src[h * 64 + lane];
    qd[h] = q_dst[h * 64 + lane];
  }
  int gw = blockIdx.x * 4 + (tid >> 6);
  int nw = gridDim.x * 4;
  for (int node = gw; node < n; node += nw) {
    int s0 = rowstart[node], s1 = rowstart[node + 1];
    float acc = gather_sum(h_in, colidx, s0, s1, lane);
    float xv = fmaxf(fmaf(dinv[node], acc, bv), 0.0f);
    x3[(size_t)node * 64 + lane] = f2bf(xv);
    float ps[4], pd[4];
#pragma unroll
    for (int h = 0; h < 4; h++) {
      ps[h] = wave_sum(xv * qs[h]);
      pd[h] = wave_sum(xv * qd[h]);
    }
    if (lane == 0) {
      *(float4*)&a_src[(size_t)node * 4] = make_float4(ps[0], ps[1], ps[2], ps[3]);
      *(float4*)&a_dst[(size_t)node * 4] = make_float4(pd[0], pd[1], pd[2], pd[3]);
    }
  }
}

// q[h][k] = sum_c W[k, h*64+c] * att[h][c]
__global__ void k_qpre(const float* __restrict__ W, const float* __restrict__ att_s,
                       const float* __restrict__ att_d,
                       float* __restrict__ q_src, float* __restrict__ q_dst) {
  int t = threadIdx.x;
  int h = t >> 6, k = t & 63;
  float ss = 0.0f, sd = 0.0f;
  for (int c = 0; c < 64; c++) {
    float w = W[k * 256 + h * 64 + c];
    ss = fmaf(w, att_s[h * 64 + c], ss);
    sd = fmaf(w, att_d[h * 64 + c], sd);
  }
  q_src[h * 64 + k] = ss;
  q_dst[h * 64 + k] = sd;
}

// ---------------- K5a: GAT softmax-aggregate in x-space ----------
__global__ __launch_bounds__(256) void k_gat_gather(
    const ushort_t* __restrict__ x3, const float* __restrict__ a_src,
    const float* __restrict__ a_dst, const int* __restrict__ rowstart,
    const int* __restrict__ colidx, ushort_t* __restrict__ Ahi,
    ushort_t* __restrict__ Alo, int n) {
  int node = (blockIdx.x * blockDim.x + threadIdx.x) >> 6;
  int lane = threadIdx.x & 63;
  if (node >= n) return;
  const float4 adv = *(const float4*)&a_dst[(size_t)node * 4];
  int s0 = rowstart[node], s1 = rowstart[node + 1];
  float acc0 = 0, acc1 = 0, acc2 = 0, acc3 = 0;
  float S0 = 0, S1 = 0, S2 = 0, S3 = 0;
  for (int base = s0; base < s1; base += 64) {
    int cnt = min(64, s1 - base);
    bool act = (lane < cnt);
    int myidx = act ? colidx[base + lane] : 0;
    float w0 = 0, w1 = 0, w2 = 0, w3 = 0;
    if (act) {
      const float4 as = *(const float4*)&a_src[(size_t)myidx * 4];
      float e0 = as.x + adv.x; e0 = (e0 > 0.f) ? e0 : 0.2f * e0; w0 = __expf(e0);
      float e1 = as.y + adv.y; e1 = (e1 > 0.f) ? e1 : 0.2f * e1; w1 = __expf(e1);
      float e2 = as.z + adv.z; e2 = (e2 > 0.f) ? e2 : 0.2f * e2; w2 = __expf(e2);
      float e3 = as.w + adv.w; e3 = (e3 > 0.f) ? e3 : 0.2f * e3; w3 = __expf(e3);
    }
    S0 += wave_sum(w0); S1 += wave_sum(w1);
    S2 += wave_sum(w2); S3 += wave_sum(w3);
    int k = 0;
    for (; k + 1 < cnt; k += 2) {
      int sa = ilanebcast(myidx, k);
      int sb = ilanebcast(myidx, k + 1);
      float wa0 = lanebcast(w0, k), wb0 = lanebcast(w0, k + 1);
      float wa1 = lanebcast(w1, k), wb1 = lanebcast(w1, k + 1);
      float wa2 = lanebcast(w2, k), wb2 = lanebcast(w2, k + 1);
      float wa3 = lanebcast(w3, k), wb3 = lanebcast(w3, k + 1);
      float va = b2f(x3[(size_t)sa * 64 + lane]);
      float vb = b2f(x3[(size_t)sb * 64 + lane]);
      acc0 = fmaf(wa0, va, acc0); acc1 = fmaf(wa1, va, acc1);
      acc2 = fmaf(wa2, va, acc2); acc3 = fmaf(wa3, va, acc3);
      acc0 = fmaf(wb0, vb, acc0); acc1 = fmaf(wb1, vb, acc1);
      acc2 = fmaf(wb2, vb, acc2); acc3 = fmaf(wb3, vb, acc3);
    }
    if (k < cnt) {
      int sa = ilanebcast(myidx, k);
      float wa0 = lanebcast(w0, k), wa1 = lanebcast(w1, k);
      float wa2 = lanebcast(w2, k), wa3 = lanebcast(w3, k);
      float va = b2f(x3[(size_t)sa * 64 + lane]);
      acc0 = fmaf(wa0, va, acc0); acc1 = fmaf(wa1, va, acc1);
      acc2 = fmaf(wa2, va, acc2); acc3 = fmaf(wa3, va, acc3);
    }
  }
  float v[4] = {acc0 * (0.25f / S0), acc1 * (0.25f / S1),
                acc2 * (0.25f / S2), acc3 * (0.25f / S3)};
  size_t baseo = (size_t)node * 256 + lane;
#pragma unroll
  for (int h = 0; h < 4; h++) {
    ushort_t hb = f2bf(v[h]);
    Ahi[baseo + h * 64] = hb;
    Alo[baseo + h * 64] = f2bf(v[h] - b2f(hb));
  }
}

// ---------------- K5b: proj out = relu(agg[N,256] @ Wcat + b) via MFMA -----
__global__ __launch_bounds__(256) void k_gat_proj_mfma(
    const ushort_t* __restrict__ Ahi, const ushort_t* __restrict__ Alo,
    const ushort_t* __restrict__ Bh, const ushort_t* __restrict__ Bl,
    const float* __restrict__ bias, float* __restrict__ out, int n, int ntiles) {
  int tid = threadIdx.x, lane = tid & 63, wave = tid >> 6;
  int m = lane & 15, q = lane >> 4;
  float bv[4];
#pragma unroll
  for (int ct = 0; ct < 4; ct++) bv[ct] = bias[ct * 16 + m];
  for (int tile = blockIdx.x * 4 + wave; tile < ntiles; tile += gridDim.x * 4) {
    int ra = tile * 16 + m;
    if (ra >= n) ra = n - 1;
    const ushort_t* ahr = Ahi + (size_t)ra * 256;
    const ushort_t* alr = Alo + (size_t)ra * 256;
    f4 acc[4];
#pragma unroll
    for (int ct = 0; ct < 4; ct++) acc[ct] = (f4){0.f, 0.f, 0.f, 0.f};
#pragma unroll 2
    for (int kc = 0; kc < 8; kc++) {
      int ko = kc * 32 + q * 8;
      bf8 ah = *(const bf8*)(ahr + ko);
      bf8 al = *(const bf8*)(alr + ko);
#pragma unroll
      for (int ct = 0; ct < 4; ct++) {
        size_t boff = ((size_t)(ct * 8 + kc) * 64 + lane) * 8;
        bf8 bh = *(const bf8*)(Bh + boff);
        bf8 bl = *(const bf8*)(Bl + boff);
        acc[ct] = __builtin_amdgcn_mfma_f32_16x16x32_bf16(ah, bh, acc[ct], 0, 0, 0);
        acc[ct] = __builtin_amdgcn_mfma_f32_16x16x32_bf16(al, bh, acc[ct], 0, 0, 0);
        acc[ct] = __builtin_amdgcn_mfma_f32_16x16x32_bf16(ah, bl, acc[ct], 0, 0, 0);
      }
    }
#pragma unroll
    for (int r = 0; r < 4; r++) {
      int row = tile * 16 + q * 4 + r;
      if (row < n) {
#pragma unroll
        for (int ct = 0; ct < 4; ct++)
          out[(size_t)row * 64 + ct * 16 + m] = fmaxf(acc[ct][r] + bv[ct], 0.f);
      }
    }
  }
}

// ---------------- pooling ----------------
__global__ void k_gstart(const int* __restrict__ batch, int* gs, int n, int B) {
  int g = blockIdx.x * blockDim.x + threadIdx.x;
  if (g > B) return;
  int lo = 0, hi = n;
  while (lo < hi) {
    int mid = (lo + hi) >> 1;
    if (batch[mid] < g) lo = mid + 1; else hi = mid;
  }
  gs[g] = lo;
}

__global__ __launch_bounds__(256) void k_pool(const float* __restrict__ x,
                                              const int* __restrict__ gs,
                                              float* __restrict__ gvec, int B) {
  int g = (blockIdx.x * blockDim.x + threadIdx.x) >> 6;
  int lane = threadIdx.x & 63;
  if (g >= B) return;
  int s0 = gs[g], s1 = gs[g + 1];
  float sum = 0.0f, mx = -INFINITY;
  for (int nd = s0; nd < s1; ++nd) {
    float v = x[(size_t)nd * 64 + lane];
    sum += v;
    mx = fmaxf(mx, v);
  }
  int cnt = s1 - s0;
  float mean = sum / fmaxf((float)cnt, 1.0f);
  float mp = (cnt > 0) ? mx : 0.0f;
  gvec[g * 64 + lane] = mean + mp;
}

// ---------------- MLP head ----------------
__global__ __launch_bounds__(256) void k_mlp(const float* __restrict__ gvec,
                                             const float* __restrict__ w1,
                                             const float* __restrict__ b1,
                                             const float* __restrict__ w2,
                                             const float* __restrict__ b2,
                                             float* __restrict__ out, int B) {
  int g = blockIdx.x * blockDim.x + threadIdx.x;
  if (g >= B) return;
  float gv[64];
#pragma unroll
  for (int i = 0; i < 64; i++) gv[i] = gvec[g * 64 + i];
  float o0 = b2[0], o1 = b2[1];
  for (int j = 0; j < 32; j++) {
    float a = b1[j];
#pragma unroll
    for (int i = 0; i < 64; i++) a = fmaf(gv[i], w1[i * 32 + j], a);
    a = fmaxf(a, 0.0f);
    o0 = fmaf(a, w2[j * 2 + 0], o0);
    o1 = fmaf(a, w2[j * 2 + 1], o1);
  }
  out[g * 2 + 0] = o0;
  out[g * 2 + 1] = o1;
}

// ---------------- launch ----------------
extern "C" void kernel_launch(void* const* d_in, const int* in_sizes, int n_in,
                              void* d_out, int out_size, void* d_ws, size_t ws_size,
                              hipStream_t stream) {
  const float* x     = (const float*)d_in[0];
  const int*   ei    = (const int*)d_in[1];
  const int*   batch = (const int*)d_in[2];
  const float* w0 = (const float*)d_in[3];  const float* b0 = (const float*)d_in[4];
  const float* w1 = (const float*)d_in[5];  const float* b1 = (const float*)d_in[6];
  const float* w2 = (const float*)d_in[7];  const float* b2 = (const float*)d_in[8];
  const float* gat_w = (const float*)d_in[9];
  const float* att_s = (const float*)d_in[10];
  const float* att_d = (const float*)d_in[11];
  const float* gat_b = (const float*)d_in[12];
  const float* l1w = (const float*)d_in[13]; const float* l1b = (const float*)d_in[14];
  const float* l2w = (const float*)d_in[15]; const float* l2b = (const float*)d_in[16];

  const int N = in_sizes[0] / 128;
  const int E = in_sizes[1] / 2;
  const int B = out_size / 2;
  const int NT = (N + 15) / 16;
  const int NBUK = (N + BRANGE - 1) / BRANGE;  // 391 for N=50000 (<=512)

  char* ws = (char*)d_ws;
  size_t off = 0;
  auto alloc = [&](size_t bytes) -> void* {
    void* p = ws + off;
    off = (off + bytes + 255) & ~(size_t)255;
    return p;
  };
  int*      bcnt     = (int*)alloc((size_t)NBUK * 4);
  int*      edgebase = (int*)alloc((size_t)NBUK * 4);
  int*      gcursor  = (int*)alloc((size_t)NBUK * 4);
  int*      bedges   = (int*)alloc((size_t)E * 4);
  int*      rowstart = (int*)alloc((size_t)(N + 1) * 4);
  int*      colidx   = (int*)alloc((size_t)(E + N) * 4);
  float*    dinv     = (float*)alloc((size_t)N * 4);
  ushort_t* hbuf     = (ushort_t*)alloc((size_t)N * 64 * 2);
  ushort_t* hbuf2    = (ushort_t*)alloc((size_t)N * 64 * 2);
  ushort_t* xg       = (ushort_t*)alloc((size_t)N * 64 * 2);
  float*    gatout   = (float*)alloc((size_t)N * 64 * 4);
  ushort_t* Ahi      = (ushort_t*)alloc((size_t)N * 256 * 2);
  ushort_t* Alo      = (ushort_t*)alloc((size_t)N * 256 * 2);
  float*    a_src    = (float*)alloc((size_t)N * 4 * 4);
  float*    a_dst    = (float*)alloc((size_t)N * 4 * 4);
  float*    q_src    = (float*)alloc(4 * 64 * 4);
  float*    q_dst    = (float*)alloc(4 * 64 * 4);
  ushort_t* B0h      = (ushort_t*)alloc(4 * 4 * 64 * 8 * 2);
  ushort_t* B0l      = (ushort_t*)alloc(4 * 4 * 64 * 8 * 2);
  ushort_t* Bgh      = (ushort_t*)alloc(4 * 8 * 64 * 8 * 2);
  ushort_t* Bgl      = (ushort_t*)alloc(4 * 8 * 64 * 8 * 2);
  int*      gs       = (int*)alloc((size_t)(B + 1) * 4);
  float*    gvec     = (float*)alloc((size_t)B * 64 * 4);
  (void)ws_size; (void)n_in;

  // bucketed CSR build
  hipMemsetAsync(bcnt, 0, (size_t)NBUK * 4, stream);
  k_ehist<<<256, 256, 0, stream>>>(ei + E, bcnt, E, NBUK);
  k_espine<<<1, 512, 0, stream>>>(bcnt, edgebase, gcursor, NBUK, rowstart, N, E);
  k_ebucket<<<1024, 256, 0, stream>>>(ei, ei + E, gcursor, bedges, E);
  k_ebsort<<<NBUK, 256, 0, stream>>>(bedges, edgebase, bcnt, colidx, rowstart, dinv, N);
  // weight prep
  k_qpre<<<1, 256, 0, stream>>>(gat_w, att_s, att_d, q_src, q_dst);
  k_wswz0<<<1, 256, 0, stream>>>(w0, B0h, B0l);
  k_wswzg<<<1, 256, 0, stream>>>(gat_w, Bgh, Bgl);

  const int AGB = 2048;
  // K1: h0' = bf16(dinv * (x @ W0))  (MFMA)
  k_gemm0_mfma<<<1024, 256, 0, stream>>>(x, B0h, B0l, dinv, hbuf, N, NT);
  // K2: x1 = relu(dinv*agg(h0')+b0); h1' = bf16(dinv*(x1@W1))
  k_agg_gemm<<<AGB, 256, 0, stream>>>(hbuf, dinv, rowstart, colidx, b0, w1, hbuf2, N);
  // K3
  k_agg_gemm<<<AGB, 256, 0, stream>>>(hbuf2, dinv, rowstart, colidx, b1, w2, hbuf, N);
  // K4: x3 (bf16) + attention logits (fp32)
  k_agg_gatpre<<<AGB, 256, 0, stream>>>(hbuf, dinv, rowstart, colidx, b2,
                                        q_src, q_dst, xg, a_src, a_dst, N);
  // K5a: softmax-weighted gather in x-space -> bf16 hi/lo planes
  k_gat_gather<<<(N + 3) / 4, 256, 0, stream>>>(xg, a_src, a_dst, rowstart, colidx,
                                                Ahi, Alo, N);
  // K5b: projection via MFMA
  k_gat_proj_mfma<<<1024, 256, 0, stream>>>(Ahi, Alo, Bgh, Bgl, gat_b, gatout, N, NT);
  // pooling + head
  k_gstart<<<(B + 1 + 255) / 256, 256, 0, stream>>>(batch, gs, N, B);
  k_pool<<<(B + 3) / 4, 256, 0, stream>>>(gatout, gs, gvec, B);
  k_mlp<<<(B + 255) / 256, 256, 0, stream>>>(gvec, l1w, l1b, l2w, l2b, (float*)d_out, B);
}

// Round 8
// 474.567 us; speedup vs baseline: 1.4068x; 1.4068x over previous
//
#include <hip/hip_runtime.h>
#include <math.h>

typedef short bf8 __attribute__((ext_vector_type(8)));   // 8 bf16 in 4 VGPRs
typedef float f4 __attribute__((ext_vector_type(4)));
typedef unsigned short ushort_t;

#define BRANGE 128  // nodes per bucket (dst>>7)
#define NB_E 256    // blocks for edge hist/scatter (must match in both kernels)

// ---------------- helpers ----------------
__device__ __forceinline__ float lanebcast(float v, int l) {
  return __int_as_float(__builtin_amdgcn_readlane(__float_as_int(v), l));
}
__device__ __forceinline__ int ilanebcast(int v, int l) {
  return __builtin_amdgcn_readlane(v, l);
}

__device__ __forceinline__ float wave_sum(float v) {
#pragma unroll
  for (int off = 32; off > 0; off >>= 1) v += __shfl_xor(v, off, 64);
  return v;
}

__device__ __forceinline__ ushort_t f2bf(float x) {  // RNE fp32->bf16 bits
  unsigned int u = __float_as_uint(x);
  return (ushort_t)((u + 0x7fffu + ((u >> 16) & 1u)) >> 16);
}
__device__ __forceinline__ float b2f(ushort_t h) {
  return __uint_as_float(((unsigned int)h) << 16);
}

// ================= contention-free bucketed CSR build =================
// Phase 1: per-block LDS histogram of dst buckets -> bhist[block][bucket]
__global__ __launch_bounds__(256) void k_ehist(const int* __restrict__ dst,
                                               int* __restrict__ bhist, int E, int nbuk) {
  __shared__ int h[512];
  int b = blockIdx.x, tid = threadIdx.x;
  for (int i = tid; i < nbuk; i += 256) h[i] = 0;
  __syncthreads();
  int chunk = (E + gridDim.x - 1) / gridDim.x;
  int e0 = b * chunk, e1 = min(E, e0 + chunk);
  for (int e = e0 + tid; e < e1; e += 256) atomicAdd(&h[dst[e] >> 7], 1);
  __syncthreads();
  for (int i = tid; i < nbuk; i += 256) bhist[b * nbuk + i] = h[i];
}

// Phase 2: bucket totals + exclusive scan + per-(block,bucket) global bases.
// No atomics; bhist is rewritten in-place to write-bases.
__global__ __launch_bounds__(512) void k_espine(
    int* __restrict__ bhist, int* __restrict__ edgebase, int* __restrict__ bcnt,
    int nbuk, int nb, int* __restrict__ rowstart, int n, int E) {
  __shared__ int smem[512];
  int t = threadIdx.x;
  int colsum = 0;
  if (t < nbuk)
    for (int i = 0; i < nb; i++) colsum += bhist[i * nbuk + t];
  smem[t] = colsum;
  __syncthreads();
  for (int off = 1; off < 512; off <<= 1) {
    int v = (t >= off) ? smem[t - off] : 0;
    __syncthreads();
    smem[t] += v;
    __syncthreads();
  }
  if (t < nbuk) {
    int base = smem[t] - colsum;
    edgebase[t] = base;
    bcnt[t] = colsum;
    int run = base;
    for (int i = 0; i < nb; i++) {
      int c = bhist[i * nbuk + t];
      bhist[i * nbuk + t] = run;
      run += c;
    }
  }
  if (t == 0) rowstart[n] = E + n;
}

// Phase 3: scatter packed edges; cursors live in LDS (zero global atomics)
__global__ __launch_bounds__(256) void k_ebucket(
    const int* __restrict__ es, const int* __restrict__ ed,
    const int* __restrict__ bhist, int* __restrict__ bedges, int E, int nbuk) {
  __shared__ int cur[512];
  int b = blockIdx.x, tid = threadIdx.x;
  for (int i = tid; i < nbuk; i += 256) cur[i] = bhist[b * nbuk + i];
  __syncthreads();
  int chunk = (E + gridDim.x - 1) / gridDim.x;
  int e0 = b * chunk, e1 = min(E, e0 + chunk);
  for (int e = e0 + tid; e < e1; e += 256) {
    int s = es[e], d = ed[e];
    int pos = atomicAdd(&cur[d >> 7], 1);
    bedges[pos] = (s << 7) | (d & 127);
  }
}

// Phase 4: per-bucket counting sort -> colidx, rowstart, dinv (self-loops added)
__global__ __launch_bounds__(256) void k_ebsort(
    const int* __restrict__ bedges, const int* __restrict__ edgebase,
    const int* __restrict__ bcnt, int* __restrict__ colidx,
    int* __restrict__ rowstart, float* __restrict__ dinv, int n) {
  __shared__ int h[128];
  __shared__ int c[128];
  int b = blockIdx.x, tid = threadIdx.x;
  int nodes0 = b * BRANGE;
  int nnode = min(BRANGE, n - nodes0);
  int ebase = edgebase[b], ecnt = bcnt[b];
  int colbase = ebase + nodes0;  // prior buckets contribute edges + their self-loops
  if (tid < 128) h[tid] = (tid < nnode) ? 1 : 0;  // self-loop
  __syncthreads();
  for (int k = ebase + tid; k < ebase + ecnt; k += 256)
    atomicAdd(&h[bedges[k] & 127], 1);
  __syncthreads();
  int own = (tid < 128) ? h[tid] : 0;  // = deg (incl self-loop)
  for (int off = 1; off < 128; off <<= 1) {
    int t = (tid >= off && tid < 128) ? h[tid - off] : 0;
    __syncthreads();
    if (tid < 128) h[tid] += t;
    __syncthreads();
  }
  if (tid < nnode) {
    int excl = h[tid] - own;
    int node = nodes0 + tid;
    rowstart[node] = colbase + excl;
    dinv[node] = 1.0f / sqrtf((float)own);
    colidx[colbase + excl] = node;  // self-loop first
    c[tid] = excl + 1;
  }
  __syncthreads();
  for (int k = ebase + tid; k < ebase + ecnt; k += 256) {
    int p = bedges[k];
    int pos = atomicAdd(&c[p & 127], 1);
    colidx[colbase + pos] = p >> 7;
  }
}

// ---------------- weight swizzle into MFMA B-fragment layout ----------------
// B-frag for 16x16x32: lane holds B[k=(lane>>4)*8+j][n=lane&15], j=0..7.

// W0 [128,64]
__global__ void k_wswz0(const float* __restrict__ W, ushort_t* __restrict__ Bh,
                        ushort_t* __restrict__ Bl) {
  for (int e = threadIdx.x; e < 4 * 4 * 64; e += 256) {
    int lane = e & 63, kc = (e >> 6) & 3, ct = e >> 8;
    int k0 = kc * 32 + (lane >> 4) * 8;
    int col = ct * 16 + (lane & 15);
#pragma unroll
    for (int j = 0; j < 8; j++) {
      float w = W[(k0 + j) * 64 + col];
      ushort_t h = f2bf(w);
      Bh[(size_t)e * 8 + j] = h;
      Bl[(size_t)e * 8 + j] = f2bf(w - b2f(h));
    }
  }
}

// Wg_cat [256,64]: Wcat[k=h*64+c][col] = gat_w[c*256 + h*64 + col]
__global__ void k_wswzg(const float* __restrict__ W, ushort_t* __restrict__ Bh,
                        ushort_t* __restrict__ Bl) {
  for (int e = threadIdx.x; e < 4 * 8 * 64; e += 256) {
    int lane = e & 63, kc = (e >> 6) & 7, ct = e >> 9;
    int k0 = kc * 32 + (lane >> 4) * 8;
    int col = ct * 16 + (lane & 15);
#pragma unroll
    for (int j = 0; j < 8; j++) {
      int k = k0 + j;
      float w = W[(k & 63) * 256 + (k >> 6) * 64 + col];
      ushort_t h = f2bf(w);
      Bh[(size_t)e * 8 + j] = h;
      Bl[(size_t)e * 8 + j] = f2bf(w - b2f(h));
    }
  }
}

// ---------------- K1: H0'[N,64] = bf16(dinv[n] * (X[N,128] @ W0)) via MFMA --
__global__ __launch_bounds__(256) void k_gemm0_mfma(
    const float* __restrict__ X, const ushort_t* __restrict__ Bh,
    const ushort_t* __restrict__ Bl, const float* __restrict__ dinv,
    ushort_t* __restrict__ H, int n, int ntiles) {
  int tid = threadIdx.x, lane = tid & 63, wave = tid >> 6;
  int m = lane & 15, q = lane >> 4;
  for (int tile = blockIdx.x * 4 + wave; tile < ntiles; tile += gridDim.x * 4) {
    int ra = tile * 16 + m;
    if (ra >= n) ra = n - 1;
    const float* xrow = X + (size_t)ra * 128;
    f4 acc[4];
#pragma unroll
    for (int ct = 0; ct < 4; ct++) acc[ct] = (f4){0.f, 0.f, 0.f, 0.f};
#pragma unroll 2
    for (int kc = 0; kc < 4; kc++) {
      int ko = kc * 32 + q * 8;
      float4 xa = *(const float4*)(xrow + ko);
      float4 xb = *(const float4*)(xrow + ko + 4);
      float f[8] = {xa.x, xa.y, xa.z, xa.w, xb.x, xb.y, xb.z, xb.w};
      union { ushort_t u[8]; bf8 v; } Uh, Ul;
#pragma unroll
      for (int j = 0; j < 8; j++) {
        ushort_t h = f2bf(f[j]);
        Uh.u[j] = h;
        Ul.u[j] = f2bf(f[j] - b2f(h));
      }
#pragma unroll
      for (int ct = 0; ct < 4; ct++) {
        size_t boff = ((size_t)(ct * 4 + kc) * 64 + lane) * 8;
        bf8 bh = *(const bf8*)(Bh + boff);
        bf8 bl = *(const bf8*)(Bl + boff);
        acc[ct] = __builtin_amdgcn_mfma_f32_16x16x32_bf16(Uh.v, bh, acc[ct], 0, 0, 0);
        acc[ct] = __builtin_amdgcn_mfma_f32_16x16x32_bf16(Ul.v, bh, acc[ct], 0, 0, 0);
        acc[ct] = __builtin_amdgcn_mfma_f32_16x16x32_bf16(Uh.v, bl, acc[ct], 0, 0, 0);
      }
    }
#pragma unroll
    for (int r = 0; r < 4; r++) {
      int row = tile * 16 + q * 4 + r;
      if (row < n) {
        float dv = dinv[row];
#pragma unroll
        for (int ct = 0; ct < 4; ct++)
          H[(size_t)row * 64 + ct * 16 + m] = f2bf(acc[ct][r] * dv);
      }
    }
  }
}

// ---------------- gather core (bf16 rows) ----------------
__device__ __forceinline__ float gather_sum(const ushort_t* __restrict__ h_in,
                                            const int* __restrict__ colidx,
                                            int s0, int s1, int lane) {
  float acc = 0.0f, accB = 0.0f;
  for (int base = s0; base < s1; base += 64) {
    int cnt = min(64, s1 - base);
    int myidx = (lane < cnt) ? colidx[base + lane] : 0;
    int k = 0;
    for (; k + 3 < cnt; k += 4) {
      int sa = ilanebcast(myidx, k);
      int sb = ilanebcast(myidx, k + 1);
      int sc = ilanebcast(myidx, k + 2);
      int sd = ilanebcast(myidx, k + 3);
      float va = b2f(h_in[(size_t)sa * 64 + lane]);
      float vb = b2f(h_in[(size_t)sb * 64 + lane]);
      float vc = b2f(h_in[(size_t)sc * 64 + lane]);
      float vd = b2f(h_in[(size_t)sd * 64 + lane]);
      acc += va; accB += vb; acc += vc; accB += vd;
    }
    for (; k < cnt; k++) {
      int sa = ilanebcast(myidx, k);
      acc += b2f(h_in[(size_t)sa * 64 + lane]);
    }
  }
  return acc + accB;
}

// ---------------- K2/K3: fused GCN agg + next GEMM (readlane GEMV) --------
__global__ __launch_bounds__(256) void k_agg_gemm(
    const ushort_t* __restrict__ h_in, const float* __restrict__ dinv,
    const int* __restrict__ rowstart, const int* __restrict__ colidx,
    const float* __restrict__ bias, const float* __restrict__ Wn,
    ushort_t* __restrict__ h_out, int n) {
  __shared__ float lds_w[64 * 64];
  int tid = threadIdx.x;
  for (int idx = tid; idx < 64 * 64; idx += 256) lds_w[idx] = Wn[idx];
  __syncthreads();
  int lane = tid & 63;
  float bv = bias[lane];
  int gw = blockIdx.x * 4 + (tid >> 6);
  int nw = gridDim.x * 4;
  for (int node = gw; node < n; node += nw) {
    int s0 = rowstart[node], s1 = rowstart[node + 1];
    float acc = gather_sum(h_in, colidx, s0, s1, lane);
    float dvn = dinv[node];
    float x1 = fmaxf(fmaf(dvn, acc, bv), 0.0f);
    float o = 0.0f;
#pragma unroll 8
    for (int k = 0; k < 64; k++)
      o = fmaf(lanebcast(x1, k), lds_w[k * 64 + lane], o);
    h_out[(size_t)node * 64 + lane] = f2bf(o * dvn);
  }
}

// ---------------- K4: GCN layer-2 agg + GAT attention logits ----------------
__global__ __launch_bounds__(256) void k_agg_gatpre(
    const ushort_t* __restrict__ h_in, const float* __restrict__ dinv,
    const int* __restrict__ rowstart, const int* __restrict__ colidx,
    const float* __restrict__ bias,
    const float* __restrict__ q_src, const float* __restrict__ q_dst,
    ushort_t* __restrict__ x3, float* __restrict__ a_src, float* __restrict__ a_dst,
    int n) {
  int tid = threadIdx.x;
  int lane = tid & 63;
  float bv = bias[lane];
  float qs[4], qd[4];
#pragma unroll
  for (int h = 0; h < 4; h++) {
    qs[h] = q_src[h * 64 + lane];
    qd[h] = q_dst[h * 64 + lane];
  }
  int gw = blockIdx.x * 4 + (tid >> 6);
  int nw = gridDim.x * 4;
  for (int node = gw; node < n; node += nw) {
    int s0 = rowstart[node], s1 = rowstart[node + 1];
    float acc = gather_sum(h_in, colidx, s0, s1, lane);
    float xv = fmaxf(fmaf(dinv[node], acc, bv), 0.0f);
    x3[(size_t)node * 64 + lane] = f2bf(xv);
    float ps[4], pd[4];
#pragma unroll
    for (int h = 0; h < 4; h++) {
      ps[h] = wave_sum(xv * qs[h]);
      pd[h] = wave_sum(xv * qd[h]);
    }
    if (lane == 0) {
      *(float4*)&a_src[(size_t)node * 4] = make_float4(ps[0], ps[1], ps[2], ps[3]);
      *(float4*)&a_dst[(size_t)node * 4] = make_float4(pd[0], pd[1], pd[2], pd[3]);
    }
  }
}

// q[h][k] = sum_c W[k, h*64+c] * att[h][c]
__global__ void k_qpre(const float* __restrict__ W, const float* __restrict__ att_s,
                       const float* __restrict__ att_d,
                       float* __restrict__ q_src, float* __restrict__ q_dst) {
  int t = threadIdx.x;
  int h = t >> 6, k = t & 63;
  float ss = 0.0f, sd = 0.0f;
  for (int c = 0; c < 64; c++) {
    float w = W[k * 256 + h * 64 + c];
    ss = fmaf(w, att_s[h * 64 + c], ss);
    sd = fmaf(w, att_d[h * 64 + c], sd);
  }
  q_src[h * 64 + k] = ss;
  q_dst[h * 64 + k] = sd;
}

// ---------------- K5a: GAT softmax-aggregate in x-space ----------
__global__ __launch_bounds__(256) void k_gat_gather(
    const ushort_t* __restrict__ x3, const float* __restrict__ a_src,
    const float* __restrict__ a_dst, const int* __restrict__ rowstart,
    const int* __restrict__ colidx, ushort_t* __restrict__ Ahi,
    ushort_t* __restrict__ Alo, int n) {
  int node = (blockIdx.x * blockDim.x + threadIdx.x) >> 6;
  int lane = threadIdx.x & 63;
  if (node >= n) return;
  const float4 adv = *(const float4*)&a_dst[(size_t)node * 4];
  int s0 = rowstart[node], s1 = rowstart[node + 1];
  float acc0 = 0, acc1 = 0, acc2 = 0, acc3 = 0;
  float S0 = 0, S1 = 0, S2 = 0, S3 = 0;
  for (int base = s0; base < s1; base += 64) {
    int cnt = min(64, s1 - base);
    bool act = (lane < cnt);
    int myidx = act ? colidx[base + lane] : 0;
    float w0 = 0, w1 = 0, w2 = 0, w3 = 0;
    if (act) {
      const float4 as = *(const float4*)&a_src[(size_t)myidx * 4];
      float e0 = as.x + adv.x; e0 = (e0 > 0.f) ? e0 : 0.2f * e0; w0 = __expf(e0);
      float e1 = as.y + adv.y; e1 = (e1 > 0.f) ? e1 : 0.2f * e1; w1 = __expf(e1);
      float e2 = as.z + adv.z; e2 = (e2 > 0.f) ? e2 : 0.2f * e2; w2 = __expf(e2);
      float e3 = as.w + adv.w; e3 = (e3 > 0.f) ? e3 : 0.2f * e3; w3 = __expf(e3);
    }
    S0 += wave_sum(w0); S1 += wave_sum(w1);
    S2 += wave_sum(w2); S3 += wave_sum(w3);
    int k = 0;
    for (; k + 1 < cnt; k += 2) {
      int sa = ilanebcast(myidx, k);
      int sb = ilanebcast(myidx, k + 1);
      float wa0 = lanebcast(w0, k), wb0 = lanebcast(w0, k + 1);
      float wa1 = lanebcast(w1, k), wb1 = lanebcast(w1, k + 1);
      float wa2 = lanebcast(w2, k), wb2 = lanebcast(w2, k + 1);
      float wa3 = lanebcast(w3, k), wb3 = lanebcast(w3, k + 1);
      float va = b2f(x3[(size_t)sa * 64 + lane]);
      float vb = b2f(x3[(size_t)sb * 64 + lane]);
      acc0 = fmaf(wa0, va, acc0); acc1 = fmaf(wa1, va, acc1);
      acc2 = fmaf(wa2, va, acc2); acc3 = fmaf(wa3, va, acc3);
      acc0 = fmaf(wb0, vb, acc0); acc1 = fmaf(wb1, vb, acc1);
      acc2 = fmaf(wb2, vb, acc2); acc3 = fmaf(wb3, vb, acc3);
    }
    if (k < cnt) {
      int sa = ilanebcast(myidx, k);
      float wa0 = lanebcast(w0, k), wa1 = lanebcast(w1, k);
      float wa2 = lanebcast(w2, k), wa3 = lanebcast(w3, k);
      float va = b2f(x3[(size_t)sa * 64 + lane]);
      acc0 = fmaf(wa0, va, acc0); acc1 = fmaf(wa1, va, acc1);
      acc2 = fmaf(wa2, va, acc2); acc3 = fmaf(wa3, va, acc3);
    }
  }
  float v[4] = {acc0 * (0.25f / S0), acc1 * (0.25f / S1),
                acc2 * (0.25f / S2), acc3 * (0.25f / S3)};
  size_t baseo = (size_t)node * 256 + lane;
#pragma unroll
  for (int h = 0; h < 4; h++) {
    ushort_t hb = f2bf(v[h]);
    Ahi[baseo + h * 64] = hb;
    Alo[baseo + h * 64] = f2bf(v[h] - b2f(hb));
  }
}

// ---------------- K5b: proj out = relu(agg[N,256] @ Wcat + b) via MFMA -----
__global__ __launch_bounds__(256) void k_gat_proj_mfma(
    const ushort_t* __restrict__ Ahi, const ushort_t* __restrict__ Alo,
    const ushort_t* __restrict__ Bh, const ushort_t* __restrict__ Bl,
    const float* __restrict__ bias, float* __restrict__ out, int n, int ntiles) {
  int tid = threadIdx.x, lane = tid & 63, wave = tid >> 6;
  int m = lane & 15, q = lane >> 4;
  float bv[4];
#pragma unroll
  for (int ct = 0; ct < 4; ct++) bv[ct] = bias[ct * 16 + m];
  for (int tile = blockIdx.x * 4 + wave; tile < ntiles; tile += gridDim.x * 4) {
    int ra = tile * 16 + m;
    if (ra >= n) ra = n - 1;
    const ushort_t* ahr = Ahi + (size_t)ra * 256;
    const ushort_t* alr = Alo + (size_t)ra * 256;
    f4 acc[4];
#pragma unroll
    for (int ct = 0; ct < 4; ct++) acc[ct] = (f4){0.f, 0.f, 0.f, 0.f};
#pragma unroll 2
    for (int kc = 0; kc < 8; kc++) {
      int ko = kc * 32 + q * 8;
      bf8 ah = *(const bf8*)(ahr + ko);
      bf8 al = *(const bf8*)(alr + ko);
#pragma unroll
      for (int ct = 0; ct < 4; ct++) {
        size_t boff = ((size_t)(ct * 8 + kc) * 64 + lane) * 8;
        bf8 bh = *(const bf8*)(Bh + boff);
        bf8 bl = *(const bf8*)(Bl + boff);
        acc[ct] = __builtin_amdgcn_mfma_f32_16x16x32_bf16(ah, bh, acc[ct], 0, 0, 0);
        acc[ct] = __builtin_amdgcn_mfma_f32_16x16x32_bf16(al, bh, acc[ct], 0, 0, 0);
        acc[ct] = __builtin_amdgcn_mfma_f32_16x16x32_bf16(ah, bl, acc[ct], 0, 0, 0);
      }
    }
#pragma unroll
    for (int r = 0; r < 4; r++) {
      int row = tile * 16 + q * 4 + r;
      if (row < n) {
#pragma unroll
        for (int ct = 0; ct < 4; ct++)
          out[(size_t)row * 64 + ct * 16 + m] = fmaxf(acc[ct][r] + bv[ct], 0.f);
      }
    }
  }
}

// ---------------- pooling ----------------
__global__ void k_gstart(const int* __restrict__ batch, int* gs, int n, int B) {
  int g = blockIdx.x * blockDim.x + threadIdx.x;
  if (g > B) return;
  int lo = 0, hi = n;
  while (lo < hi) {
    int mid = (lo + hi) >> 1;
    if (batch[mid] < g) lo = mid + 1; else hi = mid;
  }
  gs[g] = lo;
}

__global__ __launch_bounds__(256) void k_pool(const float* __restrict__ x,
                                              const int* __restrict__ gs,
                                              float* __restrict__ gvec, int B) {
  int g = (blockIdx.x * blockDim.x + threadIdx.x) >> 6;
  int lane = threadIdx.x & 63;
  if (g >= B) return;
  int s0 = gs[g], s1 = gs[g + 1];
  float sum = 0.0f, mx = -INFINITY;
  for (int nd = s0; nd < s1; ++nd) {
    float v = x[(size_t)nd * 64 + lane];
    sum += v;
    mx = fmaxf(mx, v);
  }
  int cnt = s1 - s0;
  float mean = sum / fmaxf((float)cnt, 1.0f);
  float mp = (cnt > 0) ? mx : 0.0f;
  gvec[g * 64 + lane] = mean + mp;
}

// ---------------- MLP head ----------------
__global__ __launch_bounds__(256) void k_mlp(const float* __restrict__ gvec,
                                             const float* __restrict__ w1,
                                             const float* __restrict__ b1,
                                             const float* __restrict__ w2,
                                             const float* __restrict__ b2,
                                             float* __restrict__ out, int B) {
  int g = blockIdx.x * blockDim.x + threadIdx.x;
  if (g >= B) return;
  float gv[64];
#pragma unroll
  for (int i = 0; i < 64; i++) gv[i] = gvec[g * 64 + i];
  float o0 = b2[0], o1 = b2[1];
  for (int j = 0; j < 32; j++) {
    float a = b1[j];
#pragma unroll
    for (int i = 0; i < 64; i++) a = fmaf(gv[i], w1[i * 32 + j], a);
    a = fmaxf(a, 0.0f);
    o0 = fmaf(a, w2[j * 2 + 0], o0);
    o1 = fmaf(a, w2[j * 2 + 1], o1);
  }
  out[g * 2 + 0] = o0;
  out[g * 2 + 1] = o1;
}

// ---------------- launch ----------------
extern "C" void kernel_launch(void* const* d_in, const int* in_sizes, int n_in,
                              void* d_out, int out_size, void* d_ws, size_t ws_size,
                              hipStream_t stream) {
  const float* x     = (const float*)d_in[0];
  const int*   ei    = (const int*)d_in[1];
  const int*   batch = (const int*)d_in[2];
  const float* w0 = (const float*)d_in[3];  const float* b0 = (const float*)d_in[4];
  const float* w1 = (const float*)d_in[5];  const float* b1 = (const float*)d_in[6];
  const float* w2 = (const float*)d_in[7];  const float* b2 = (const float*)d_in[8];
  const float* gat_w = (const float*)d_in[9];
  const float* att_s = (const float*)d_in[10];
  const float* att_d = (const float*)d_in[11];
  const float* gat_b = (const float*)d_in[12];
  const float* l1w = (const float*)d_in[13]; const float* l1b = (const float*)d_in[14];
  const float* l2w = (const float*)d_in[15]; const float* l2b = (const float*)d_in[16];

  const int N = in_sizes[0] / 128;
  const int E = in_sizes[1] / 2;
  const int B = out_size / 2;
  const int NT = (N + 15) / 16;
  const int NBUK = (N + BRANGE - 1) / BRANGE;  // 391 for N=50000 (<=512)

  char* ws = (char*)d_ws;
  size_t off = 0;
  auto alloc = [&](size_t bytes) -> void* {
    void* p = ws + off;
    off = (off + bytes + 255) & ~(size_t)255;
    return p;
  };
  int*      bhist    = (int*)alloc((size_t)NB_E * NBUK * 4);
  int*      edgebase = (int*)alloc((size_t)NBUK * 4);
  int*      bcnt     = (int*)alloc((size_t)NBUK * 4);
  int*      bedges   = (int*)alloc((size_t)E * 4);
  int*      rowstart = (int*)alloc((size_t)(N + 1) * 4);
  int*      colidx   = (int*)alloc((size_t)(E + N) * 4);
  float*    dinv     = (float*)alloc((size_t)N * 4);
  ushort_t* hbuf     = (ushort_t*)alloc((size_t)N * 64 * 2);
  ushort_t* hbuf2    = (ushort_t*)alloc((size_t)N * 64 * 2);
  ushort_t* xg       = (ushort_t*)alloc((size_t)N * 64 * 2);
  float*    gatout   = (float*)alloc((size_t)N * 64 * 4);
  ushort_t* Ahi      = (ushort_t*)alloc((size_t)N * 256 * 2);
  ushort_t* Alo      = (ushort_t*)alloc((size_t)N * 256 * 2);
  float*    a_src    = (float*)alloc((size_t)N * 4 * 4);
  float*    a_dst    = (float*)alloc((size_t)N * 4 * 4);
  float*    q_src    = (float*)alloc(4 * 64 * 4);
  float*    q_dst    = (float*)alloc(4 * 64 * 4);
  ushort_t* B0h      = (ushort_t*)alloc(4 * 4 * 64 * 8 * 2);
  ushort_t* B0l      = (ushort_t*)alloc(4 * 4 * 64 * 8 * 2);
  ushort_t* Bgh      = (ushort_t*)alloc(4 * 8 * 64 * 8 * 2);
  ushort_t* Bgl      = (ushort_t*)alloc(4 * 8 * 64 * 8 * 2);
  int*      gs       = (int*)alloc((size_t)(B + 1) * 4);
  float*    gvec     = (float*)alloc((size_t)B * 64 * 4);
  (void)ws_size; (void)n_in;

  // contention-free bucketed CSR build
  k_ehist<<<NB_E, 256, 0, stream>>>(ei + E, bhist, E, NBUK);
  k_espine<<<1, 512, 0, stream>>>(bhist, edgebase, bcnt, NBUK, NB_E, rowstart, N, E);
  k_ebucket<<<NB_E, 256, 0, stream>>>(ei, ei + E, bhist, bedges, E, NBUK);
  k_ebsort<<<NBUK, 256, 0, stream>>>(bedges, edgebase, bcnt, colidx, rowstart, dinv, N);
  // weight prep
  k_qpre<<<1, 256, 0, stream>>>(gat_w, att_s, att_d, q_src, q_dst);
  k_wswz0<<<1, 256, 0, stream>>>(w0, B0h, B0l);
  k_wswzg<<<1, 256, 0, stream>>>(gat_w, Bgh, Bgl);

  const int AGB = 2048;
  // K1: h0' = bf16(dinv * (x @ W0))  (MFMA)
  k_gemm0_mfma<<<1024, 256, 0, stream>>>(x, B0h, B0l, dinv, hbuf, N, NT);
  // K2: x1 = relu(dinv*agg(h0')+b0); h1' = bf16(dinv*(x1@W1))
  k_agg_gemm<<<AGB, 256, 0, stream>>>(hbuf, dinv, rowstart, colidx, b0, w1, hbuf2, N);
  // K3
  k_agg_gemm<<<AGB, 256, 0, stream>>>(hbuf2, dinv, rowstart, colidx, b1, w2, hbuf, N);
  // K4: x3 (bf16) + attention logits (fp32)
  k_agg_gatpre<<<AGB, 256, 0, stream>>>(hbuf, dinv, rowstart, colidx, b2,
                                        q_src, q_dst, xg, a_src, a_dst, N);
  // K5a: softmax-weighted gather in x-space -> bf16 hi/lo planes
  k_gat_gather<<<(N + 3) / 4, 256, 0, stream>>>(xg, a_src, a_dst, rowstart, colidx,
                                                Ahi, Alo, N);
  // K5b: projection via MFMA
  k_gat_proj_mfma<<<1024, 256, 0, stream>>>(Ahi, Alo, Bgh, Bgl, gat_b, gatout, N, NT);
  // pooling + head
  k_gstart<<<(B + 1 + 255) / 256, 256, 0, stream>>>(batch, gs, N, B);
  k_pool<<<(B + 3) / 4, 256, 0, stream>>>(gatout, gs, gvec, B);
  k_mlp<<<(B + 255) / 256, 256, 0, stream>>>(gvec, l1w, l1b, l2w, l2b, (float*)d_out, B);
}

// Round 9
// 388.231 us; speedup vs baseline: 1.7197x; 1.2224x over previous
//
#include <hip/hip_runtime.h>
#include <math.h>

typedef short bf8 __attribute__((ext_vector_type(8)));   // 8 bf16 in 4 VGPRs
typedef float f4 __attribute__((ext_vector_type(4)));
typedef unsigned short ushort_t;

#define BRANGE 128  // nodes per bucket (dst>>7)
#define NB_E 256    // blocks for edge hist/scatter

// ---------------- helpers ----------------
__device__ __forceinline__ float lanebcast(float v, int l) {
  return __int_as_float(__builtin_amdgcn_readlane(__float_as_int(v), l));
}
__device__ __forceinline__ int ilanebcast(int v, int l) {
  return __builtin_amdgcn_readlane(v, l);
}

__device__ __forceinline__ float wave_sum(float v) {
#pragma unroll
  for (int off = 32; off > 0; off >>= 1) v += __shfl_xor(v, off, 64);
  return v;
}

__device__ __forceinline__ ushort_t f2bf(float x) {  // RNE fp32->bf16 bits
  unsigned int u = __float_as_uint(x);
  return (ushort_t)((u + 0x7fffu + ((u >> 16) & 1u)) >> 16);
}
__device__ __forceinline__ float b2f(ushort_t h) {
  return __uint_as_float(((unsigned int)h) << 16);
}

// ================= contention-free bucketed CSR build =================
// bhistT layout: [bucket][block] (columns contiguous per bucket)

// Phase 1: per-block LDS histogram of dst buckets
__global__ __launch_bounds__(256) void k_ehist(const int* __restrict__ dst,
                                               int* __restrict__ bhistT, int E, int nbuk) {
  __shared__ int h[512];
  int b = blockIdx.x, tid = threadIdx.x;
  for (int i = tid; i < nbuk; i += 256) h[i] = 0;
  __syncthreads();
  int chunk = (E + gridDim.x - 1) / gridDim.x;
  int e0 = b * chunk, e1 = min(E, e0 + chunk);
  for (int e = e0 + tid; e < e1; e += 256) atomicAdd(&h[dst[e] >> 7], 1);
  __syncthreads();
  for (int i = tid; i < nbuk; i += 256) bhistT[i * NB_E + b] = h[i];
}

// Phase 2a: bucket totals (one block per bucket, coalesced column)
__global__ __launch_bounds__(256) void k_btot(const int* __restrict__ bhistT,
                                              int* __restrict__ bcnt, int nb) {
  __shared__ int sm[256];
  int b = blockIdx.x, tid = threadIdx.x;
  sm[tid] = (tid < nb) ? bhistT[b * NB_E + tid] : 0;
  __syncthreads();
  for (int off = 128; off > 0; off >>= 1) {
    if (tid < off) sm[tid] += sm[tid + off];
    __syncthreads();
  }
  if (tid == 0) bcnt[b] = sm[0];
}

// Phase 2b: exclusive scan of bucket totals (single block)
__global__ __launch_bounds__(512) void k_bscan(
    const int* __restrict__ bcnt, int* __restrict__ edgebase, int nbuk,
    int* __restrict__ rowstart, int n, int E) {
  __shared__ int smem[512];
  int t = threadIdx.x;
  int v = (t < nbuk) ? bcnt[t] : 0;
  smem[t] = v;
  __syncthreads();
  for (int off = 1; off < 512; off <<= 1) {
    int u = (t >= off) ? smem[t - off] : 0;
    __syncthreads();
    smem[t] += u;
    __syncthreads();
  }
  if (t < nbuk) edgebase[t] = smem[t] - v;
  if (t == 0) rowstart[n] = E + n;
}

// Phase 2c: per-(block,bucket) write bases (one block per bucket, LDS scan)
__global__ __launch_bounds__(256) void k_bbase(int* __restrict__ bhistT,
                                               const int* __restrict__ edgebase,
                                               int nb) {
  __shared__ int sm[256];
  int b = blockIdx.x, tid = threadIdx.x;
  int v = (tid < nb) ? bhistT[b * NB_E + tid] : 0;
  sm[tid] = v;
  __syncthreads();
  for (int off = 1; off < 256; off <<= 1) {
    int u = (tid >= off) ? sm[tid - off] : 0;
    __syncthreads();
    sm[tid] += u;
    __syncthreads();
  }
  if (tid < nb) bhistT[b * NB_E + tid] = edgebase[b] + sm[tid] - v;
}

// Phase 3: scatter packed edges; cursors live in LDS (zero global atomics)
__global__ __launch_bounds__(256) void k_ebucket(
    const int* __restrict__ es, const int* __restrict__ ed,
    const int* __restrict__ bhistT, int* __restrict__ bedges, int E, int nbuk) {
  __shared__ int cur[512];
  int b = blockIdx.x, tid = threadIdx.x;
  for (int i = tid; i < nbuk; i += 256) cur[i] = bhistT[i * NB_E + b];
  __syncthreads();
  int chunk = (E + gridDim.x - 1) / gridDim.x;
  int e0 = b * chunk, e1 = min(E, e0 + chunk);
  for (int e = e0 + tid; e < e1; e += 256) {
    int s = es[e], d = ed[e];
    int pos = atomicAdd(&cur[d >> 7], 1);
    bedges[pos] = (s << 7) | (d & 127);
  }
}

// Phase 4: per-bucket counting sort -> colidx, rowstart, dinv (self-loops added)
__global__ __launch_bounds__(256) void k_ebsort(
    const int* __restrict__ bedges, const int* __restrict__ edgebase,
    const int* __restrict__ bcnt, int* __restrict__ colidx,
    int* __restrict__ rowstart, float* __restrict__ dinv, int n) {
  __shared__ int h[128];
  __shared__ int c[128];
  int b = blockIdx.x, tid = threadIdx.x;
  int nodes0 = b * BRANGE;
  int nnode = min(BRANGE, n - nodes0);
  int ebase = edgebase[b], ecnt = bcnt[b];
  int colbase = ebase + nodes0;
  if (tid < 128) h[tid] = (tid < nnode) ? 1 : 0;  // self-loop
  __syncthreads();
  for (int k = ebase + tid; k < ebase + ecnt; k += 256)
    atomicAdd(&h[bedges[k] & 127], 1);
  __syncthreads();
  int own = (tid < 128) ? h[tid] : 0;  // = deg (incl self-loop)
  for (int off = 1; off < 128; off <<= 1) {
    int t = (tid >= off && tid < 128) ? h[tid - off] : 0;
    __syncthreads();
    if (tid < 128) h[tid] += t;
    __syncthreads();
  }
  if (tid < nnode) {
    int excl = h[tid] - own;
    int node = nodes0 + tid;
    rowstart[node] = colbase + excl;
    dinv[node] = 1.0f / sqrtf((float)own);
    colidx[colbase + excl] = node;  // self-loop first
    c[tid] = excl + 1;
  }
  __syncthreads();
  for (int k = ebase + tid; k < ebase + ecnt; k += 256) {
    int p = bedges[k];
    int pos = atomicAdd(&c[p & 127], 1);
    colidx[colbase + pos] = p >> 7;
  }
}

// ---------------- weight swizzle into MFMA B-fragment layout ----------------
// B-frag for 16x16x32: lane holds B[k=(lane>>4)*8+j][n=lane&15], j=0..7.

// W0 [128,64] (4*4*64 = 1024 frag-entries)
__global__ void k_wswz0(const float* __restrict__ W, ushort_t* __restrict__ Bh,
                        ushort_t* __restrict__ Bl) {
  int e = blockIdx.x * 256 + threadIdx.x;
  if (e >= 4 * 4 * 64) return;
  int lane = e & 63, kc = (e >> 6) & 3, ct = e >> 8;
  int k0 = kc * 32 + (lane >> 4) * 8;
  int col = ct * 16 + (lane & 15);
#pragma unroll
  for (int j = 0; j < 8; j++) {
    float w = W[(k0 + j) * 64 + col];
    ushort_t h = f2bf(w);
    Bh[(size_t)e * 8 + j] = h;
    Bl[(size_t)e * 8 + j] = f2bf(w - b2f(h));
  }
}

// Wg_cat [256,64] (4*8*64 = 2048 frag-entries)
__global__ void k_wswzg(const float* __restrict__ W, ushort_t* __restrict__ Bh,
                        ushort_t* __restrict__ Bl) {
  int e = blockIdx.x * 256 + threadIdx.x;
  if (e >= 4 * 8 * 64) return;
  int lane = e & 63, kc = (e >> 6) & 7, ct = e >> 9;
  int k0 = kc * 32 + (lane >> 4) * 8;
  int col = ct * 16 + (lane & 15);
#pragma unroll
  for (int j = 0; j < 8; j++) {
    int k = k0 + j;
    float w = W[(k & 63) * 256 + (k >> 6) * 64 + col];
    ushort_t h = f2bf(w);
    Bh[(size_t)e * 8 + j] = h;
    Bl[(size_t)e * 8 + j] = f2bf(w - b2f(h));
  }
}

// ---------------- K1: H0'[N,64] = bf16(dinv[n] * (X[N,128] @ W0)) via MFMA --
__global__ __launch_bounds__(256) void k_gemm0_mfma(
    const float* __restrict__ X, const ushort_t* __restrict__ Bh,
    const ushort_t* __restrict__ Bl, const float* __restrict__ dinv,
    ushort_t* __restrict__ H, int n, int ntiles) {
  int tid = threadIdx.x, lane = tid & 63, wave = tid >> 6;
  int m = lane & 15, q = lane >> 4;
  for (int tile = blockIdx.x * 4 + wave; tile < ntiles; tile += gridDim.x * 4) {
    int ra = tile * 16 + m;
    if (ra >= n) ra = n - 1;
    const float* xrow = X + (size_t)ra * 128;
    f4 acc[4];
#pragma unroll
    for (int ct = 0; ct < 4; ct++) acc[ct] = (f4){0.f, 0.f, 0.f, 0.f};
#pragma unroll 2
    for (int kc = 0; kc < 4; kc++) {
      int ko = kc * 32 + q * 8;
      float4 xa = *(const float4*)(xrow + ko);
      float4 xb = *(const float4*)(xrow + ko + 4);
      float f[8] = {xa.x, xa.y, xa.z, xa.w, xb.x, xb.y, xb.z, xb.w};
      union { ushort_t u[8]; bf8 v; } Uh, Ul;
#pragma unroll
      for (int j = 0; j < 8; j++) {
        ushort_t h = f2bf(f[j]);
        Uh.u[j] = h;
        Ul.u[j] = f2bf(f[j] - b2f(h));
      }
#pragma unroll
      for (int ct = 0; ct < 4; ct++) {
        size_t boff = ((size_t)(ct * 4 + kc) * 64 + lane) * 8;
        bf8 bh = *(const bf8*)(Bh + boff);
        bf8 bl = *(const bf8*)(Bl + boff);
        acc[ct] = __builtin_amdgcn_mfma_f32_16x16x32_bf16(Uh.v, bh, acc[ct], 0, 0, 0);
        acc[ct] = __builtin_amdgcn_mfma_f32_16x16x32_bf16(Ul.v, bh, acc[ct], 0, 0, 0);
        acc[ct] = __builtin_amdgcn_mfma_f32_16x16x32_bf16(Uh.v, bl, acc[ct], 0, 0, 0);
      }
    }
#pragma unroll
    for (int r = 0; r < 4; r++) {
      int row = tile * 16 + q * 4 + r;
      if (row < n) {
        float dv = dinv[row];
#pragma unroll
        for (int ct = 0; ct < 4; ct++)
          H[(size_t)row * 64 + ct * 16 + m] = f2bf(acc[ct][r] * dv);
      }
    }
  }
}

// ---------------- gather core (bf16 rows) ----------------
__device__ __forceinline__ float gather_sum(const ushort_t* __restrict__ h_in,
                                            const int* __restrict__ colidx,
                                            int s0, int s1, int lane) {
  float acc = 0.0f, accB = 0.0f;
  for (int base = s0; base < s1; base += 64) {
    int cnt = min(64, s1 - base);
    int myidx = (lane < cnt) ? colidx[base + lane] : 0;
    int k = 0;
    for (; k + 3 < cnt; k += 4) {
      int sa = ilanebcast(myidx, k);
      int sb = ilanebcast(myidx, k + 1);
      int sc = ilanebcast(myidx, k + 2);
      int sd = ilanebcast(myidx, k + 3);
      float va = b2f(h_in[(size_t)sa * 64 + lane]);
      float vb = b2f(h_in[(size_t)sb * 64 + lane]);
      float vc = b2f(h_in[(size_t)sc * 64 + lane]);
      float vd = b2f(h_in[(size_t)sd * 64 + lane]);
      acc += va; accB += vb; acc += vc; accB += vd;
    }
    for (; k < cnt; k++) {
      int sa = ilanebcast(myidx, k);
      acc += b2f(h_in[(size_t)sa * 64 + lane]);
    }
  }
  return acc + accB;
}

// ---------------- K2/K3: fused GCN agg + next GEMM (readlane GEMV) --------
__global__ __launch_bounds__(256) void k_agg_gemm(
    const ushort_t* __restrict__ h_in, const float* __restrict__ dinv,
    const int* __restrict__ rowstart, const int* __restrict__ colidx,
    const float* __restrict__ bias, const float* __restrict__ Wn,
    ushort_t* __restrict__ h_out, int n) {
  __shared__ float lds_w[64 * 64];
  int tid = threadIdx.x;
  for (int idx = tid; idx < 64 * 64; idx += 256) lds_w[idx] = Wn[idx];
  __syncthreads();
  int lane = tid & 63;
  float bv = bias[lane];
  int gw = blockIdx.x * 4 + (tid >> 6);
  int nw = gridDim.x * 4;
  for (int node = gw; node < n; node += nw) {
    int s0 = rowstart[node], s1 = rowstart[node + 1];
    float acc = gather_sum(h_in, colidx, s0, s1, lane);
    float dvn = dinv[node];
    float x1 = fmaxf(fmaf(dvn, acc, bv), 0.0f);
    float o = 0.0f;
#pragma unroll 8
    for (int k = 0; k < 64; k++)
      o = fmaf(lanebcast(x1, k), lds_w[k * 64 + lane], o);
    h_out[(size_t)node * 64 + lane] = f2bf(o * dvn);
  }
}

// ---------------- K4: GCN layer-2 agg + GAT attention logits ----------------
__global__ __launch_bounds__(256) void k_agg_gatpre(
    const ushort_t* __restrict__ h_in, const float* __restrict__ dinv,
    const int* __restrict__ rowstart, const int* __restrict__ colidx,
    const float* __restrict__ bias,
    const float* __restrict__ q_src, const float* __restrict__ q_dst,
    ushort_t* __restrict__ x3, float* __restrict__ a_src, float* __restrict__ a_dst,
    int n) {
  int tid = threadIdx.x;
  int lane = tid & 63;
  float bv = bias[lane];
  float qs[4], qd[4];
#pragma unroll
  for (int h = 0; h < 4; h++) {
    qs[h] = q_src[h * 64 + lane];
    qd[h] = q_dst[h * 64 + lane];
  }
  int gw = blockIdx.x * 4 + (tid >> 6);
  int nw = gridDim.x * 4;
  for (int node = gw; node < n; node += nw) {
    int s0 = rowstart[node], s1 = rowstart[node + 1];
    float acc = gather_sum(h_in, colidx, s0, s1, lane);
    float xv = fmaxf(fmaf(dinv[node], acc, bv), 0.0f);
    x3[(size_t)node * 64 + lane] = f2bf(xv);
    float ps[4], pd[4];
#pragma unroll
    for (int h = 0; h < 4; h++) {
      ps[h] = wave_sum(xv * qs[h]);
      pd[h] = wave_sum(xv * qd[h]);
    }
    if (lane == 0) {
      *(float4*)&a_src[(size_t)node * 4] = make_float4(ps[0], ps[1], ps[2], ps[3]);
      *(float4*)&a_dst[(size_t)node * 4] = make_float4(pd[0], pd[1], pd[2], pd[3]);
    }
  }
}

// q[h][k] = sum_c W[k, h*64+c] * att[h][c]
__global__ void k_qpre(const float* __restrict__ W, const float* __restrict__ att_s,
                       const float* __restrict__ att_d,
                       float* __restrict__ q_src, float* __restrict__ q_dst) {
  int t = threadIdx.x;
  int h = t >> 6, k = t & 63;
  float ss = 0.0f, sd = 0.0f;
  for (int c = 0; c < 64; c++) {
    float w = W[k * 256 + h * 64 + c];
    ss = fmaf(w, att_s[h * 64 + c], ss);
    sd = fmaf(w, att_d[h * 64 + c], sd);
  }
  q_src[h * 64 + k] = ss;
  q_dst[h * 64 + k] = sd;
}

// ---------------- K5a: GAT softmax-aggregate in x-space ----------
__global__ __launch_bounds__(256) void k_gat_gather(
    const ushort_t* __restrict__ x3, const float* __restrict__ a_src,
    const float* __restrict__ a_dst, const int* __restrict__ rowstart,
    const int* __restrict__ colidx, ushort_t* __restrict__ Ahi,
    ushort_t* __restrict__ Alo, int n) {
  int node = (blockIdx.x * blockDim.x + threadIdx.x) >> 6;
  int lane = threadIdx.x & 63;
  if (node >= n) return;
  const float4 adv = *(const float4*)&a_dst[(size_t)node * 4];
  int s0 = rowstart[node], s1 = rowstart[node + 1];
  float acc0 = 0, acc1 = 0, acc2 = 0, acc3 = 0;
  float S0 = 0, S1 = 0, S2 = 0, S3 = 0;
  for (int base = s0; base < s1; base += 64) {
    int cnt = min(64, s1 - base);
    bool act = (lane < cnt);
    int myidx = act ? colidx[base + lane] : 0;
    float w0 = 0, w1 = 0, w2 = 0, w3 = 0;
    if (act) {
      const float4 as = *(const float4*)&a_src[(size_t)myidx * 4];
      float e0 = as.x + adv.x; e0 = (e0 > 0.f) ? e0 : 0.2f * e0; w0 = __expf(e0);
      float e1 = as.y + adv.y; e1 = (e1 > 0.f) ? e1 : 0.2f * e1; w1 = __expf(e1);
      float e2 = as.z + adv.z; e2 = (e2 > 0.f) ? e2 : 0.2f * e2; w2 = __expf(e2);
      float e3 = as.w + adv.w; e3 = (e3 > 0.f) ? e3 : 0.2f * e3; w3 = __expf(e3);
    }
    S0 += wave_sum(w0); S1 += wave_sum(w1);
    S2 += wave_sum(w2); S3 += wave_sum(w3);
    int k = 0;
    for (; k + 1 < cnt; k += 2) {
      int sa = ilanebcast(myidx, k);
      int sb = ilanebcast(myidx, k + 1);
      float wa0 = lanebcast(w0, k), wb0 = lanebcast(w0, k + 1);
      float wa1 = lanebcast(w1, k), wb1 = lanebcast(w1, k + 1);
      float wa2 = lanebcast(w2, k), wb2 = lanebcast(w2, k + 1);
      float wa3 = lanebcast(w3, k), wb3 = lanebcast(w3, k + 1);
      float va = b2f(x3[(size_t)sa * 64 + lane]);
      float vb = b2f(x3[(size_t)sb * 64 + lane]);
      acc0 = fmaf(wa0, va, acc0); acc1 = fmaf(wa1, va, acc1);
      acc2 = fmaf(wa2, va, acc2); acc3 = fmaf(wa3, va, acc3);
      acc0 = fmaf(wb0, vb, acc0); acc1 = fmaf(wb1, vb, acc1);
      acc2 = fmaf(wb2, vb, acc2); acc3 = fmaf(wb3, vb, acc3);
    }
    if (k < cnt) {
      int sa = ilanebcast(myidx, k);
      float wa0 = lanebcast(w0, k), wa1 = lanebcast(w1, k);
      float wa2 = lanebcast(w2, k), wa3 = lanebcast(w3, k);
      float va = b2f(x3[(size_t)sa * 64 + lane]);
      acc0 = fmaf(wa0, va, acc0); acc1 = fmaf(wa1, va, acc1);
      acc2 = fmaf(wa2, va, acc2); acc3 = fmaf(wa3, va, acc3);
    }
  }
  float v[4] = {acc0 * (0.25f / S0), acc1 * (0.25f / S1),
                acc2 * (0.25f / S2), acc3 * (0.25f / S3)};
  size_t baseo = (size_t)node * 256 + lane;
#pragma unroll
  for (int h = 0; h < 4; h++) {
    ushort_t hb = f2bf(v[h]);
    Ahi[baseo + h * 64] = hb;
    Alo[baseo + h * 64] = f2bf(v[h] - b2f(hb));
  }
}

// ---------------- K5b: proj out = relu(agg[N,256] @ Wcat + b) via MFMA -----
__global__ __launch_bounds__(256) void k_gat_proj_mfma(
    const ushort_t* __restrict__ Ahi, const ushort_t* __restrict__ Alo,
    const ushort_t* __restrict__ Bh, const ushort_t* __restrict__ Bl,
    const float* __restrict__ bias, float* __restrict__ out, int n, int ntiles) {
  int tid = threadIdx.x, lane = tid & 63, wave = tid >> 6;
  int m = lane & 15, q = lane >> 4;
  float bv[4];
#pragma unroll
  for (int ct = 0; ct < 4; ct++) bv[ct] = bias[ct * 16 + m];
  for (int tile = blockIdx.x * 4 + wave; tile < ntiles; tile += gridDim.x * 4) {
    int ra = tile * 16 + m;
    if (ra >= n) ra = n - 1;
    const ushort_t* ahr = Ahi + (size_t)ra * 256;
    const ushort_t* alr = Alo + (size_t)ra * 256;
    f4 acc[4];
#pragma unroll
    for (int ct = 0; ct < 4; ct++) acc[ct] = (f4){0.f, 0.f, 0.f, 0.f};
#pragma unroll 2
    for (int kc = 0; kc < 8; kc++) {
      int ko = kc * 32 + q * 8;
      bf8 ah = *(const bf8*)(ahr + ko);
      bf8 al = *(const bf8*)(alr + ko);
#pragma unroll
      for (int ct = 0; ct < 4; ct++) {
        size_t boff = ((size_t)(ct * 8 + kc) * 64 + lane) * 8;
        bf8 bh = *(const bf8*)(Bh + boff);
        bf8 bl = *(const bf8*)(Bl + boff);
        acc[ct] = __builtin_amdgcn_mfma_f32_16x16x32_bf16(ah, bh, acc[ct], 0, 0, 0);
        acc[ct] = __builtin_amdgcn_mfma_f32_16x16x32_bf16(al, bh, acc[ct], 0, 0, 0);
        acc[ct] = __builtin_amdgcn_mfma_f32_16x16x32_bf16(ah, bl, acc[ct], 0, 0, 0);
      }
    }
#pragma unroll
    for (int r = 0; r < 4; r++) {
      int row = tile * 16 + q * 4 + r;
      if (row < n) {
#pragma unroll
        for (int ct = 0; ct < 4; ct++)
          out[(size_t)row * 64 + ct * 16 + m] = fmaxf(acc[ct][r] + bv[ct], 0.f);
      }
    }
  }
}

// ---------------- pooling ----------------
__global__ void k_gstart(const int* __restrict__ batch, int* gs, int n, int B) {
  int g = blockIdx.x * blockDim.x + threadIdx.x;
  if (g > B) return;
  int lo = 0, hi = n;
  while (lo < hi) {
    int mid = (lo + hi) >> 1;
    if (batch[mid] < g) lo = mid + 1; else hi = mid;
  }
  gs[g] = lo;
}

__global__ __launch_bounds__(256) void k_pool(const float* __restrict__ x,
                                              const int* __restrict__ gs,
                                              float* __restrict__ gvec, int B) {
  int g = (blockIdx.x * blockDim.x + threadIdx.x) >> 6;
  int lane = threadIdx.x & 63;
  if (g >= B) return;
  int s0 = gs[g], s1 = gs[g + 1];
  float sum = 0.0f, mx = -INFINITY;
  for (int nd = s0; nd < s1; ++nd) {
    float v = x[(size_t)nd * 64 + lane];
    sum += v;
    mx = fmaxf(mx, v);
  }
  int cnt = s1 - s0;
  float mean = sum / fmaxf((float)cnt, 1.0f);
  float mp = (cnt > 0) ? mx : 0.0f;
  gvec[g * 64 + lane] = mean + mp;
}

// ---------------- MLP head ----------------
__global__ __launch_bounds__(256) void k_mlp(const float* __restrict__ gvec,
                                             const float* __restrict__ w1,
                                             const float* __restrict__ b1,
                                             const float* __restrict__ w2,
                                             const float* __restrict__ b2,
                                             float* __restrict__ out, int B) {
  int g = blockIdx.x * blockDim.x + threadIdx.x;
  if (g >= B) return;
  float gv[64];
#pragma unroll
  for (int i = 0; i < 64; i++) gv[i] = gvec[g * 64 + i];
  float o0 = b2[0], o1 = b2[1];
  for (int j = 0; j < 32; j++) {
    float a = b1[j];
#pragma unroll
    for (int i = 0; i < 64; i++) a = fmaf(gv[i], w1[i * 32 + j], a);
    a = fmaxf(a, 0.0f);
    o0 = fmaf(a, w2[j * 2 + 0], o0);
    o1 = fmaf(a, w2[j * 2 + 1], o1);
  }
  out[g * 2 + 0] = o0;
  out[g * 2 + 1] = o1;
}

// ---------------- launch ----------------
extern "C" void kernel_launch(void* const* d_in, const int* in_sizes, int n_in,
                              void* d_out, int out_size, void* d_ws, size_t ws_size,
                              hipStream_t stream) {
  const float* x     = (const float*)d_in[0];
  const int*   ei    = (const int*)d_in[1];
  const int*   batch = (const int*)d_in[2];
  const float* w0 = (const float*)d_in[3];  const float* b0 = (const float*)d_in[4];
  const float* w1 = (const float*)d_in[5];  const float* b1 = (const float*)d_in[6];
  const float* w2 = (const float*)d_in[7];  const float* b2 = (const float*)d_in[8];
  const float* gat_w = (const float*)d_in[9];
  const float* att_s = (const float*)d_in[10];
  const float* att_d = (const float*)d_in[11];
  const float* gat_b = (const float*)d_in[12];
  const float* l1w = (const float*)d_in[13]; const float* l1b = (const float*)d_in[14];
  const float* l2w = (const float*)d_in[15]; const float* l2b = (const float*)d_in[16];

  const int N = in_sizes[0] / 128;
  const int E = in_sizes[1] / 2;
  const int B = out_size / 2;
  const int NT = (N + 15) / 16;
  const int NBUK = (N + BRANGE - 1) / BRANGE;  // 391 for N=50000 (<=512)

  char* ws = (char*)d_ws;
  size_t off = 0;
  auto alloc = [&](size_t bytes) -> void* {
    void* p = ws + off;
    off = (off + bytes + 255) & ~(size_t)255;
    return p;
  };
  int*      bhistT   = (int*)alloc((size_t)NBUK * NB_E * 4);
  int*      edgebase = (int*)alloc((size_t)NBUK * 4);
  int*      bcnt     = (int*)alloc((size_t)NBUK * 4);
  int*      bedges   = (int*)alloc((size_t)E * 4);
  int*      rowstart = (int*)alloc((size_t)(N + 1) * 4);
  int*      colidx   = (int*)alloc((size_t)(E + N) * 4);
  float*    dinv     = (float*)alloc((size_t)N * 4);
  ushort_t* hbuf     = (ushort_t*)alloc((size_t)N * 64 * 2);
  ushort_t* hbuf2    = (ushort_t*)alloc((size_t)N * 64 * 2);
  ushort_t* xg       = (ushort_t*)alloc((size_t)N * 64 * 2);
  float*    gatout   = (float*)alloc((size_t)N * 64 * 4);
  ushort_t* Ahi      = (ushort_t*)alloc((size_t)N * 256 * 2);
  ushort_t* Alo      = (ushort_t*)alloc((size_t)N * 256 * 2);
  float*    a_src    = (float*)alloc((size_t)N * 4 * 4);
  float*    a_dst    = (float*)alloc((size_t)N * 4 * 4);
  float*    q_src    = (float*)alloc(4 * 64 * 4);
  float*    q_dst    = (float*)alloc(4 * 64 * 4);
  ushort_t* B0h      = (ushort_t*)alloc(4 * 4 * 64 * 8 * 2);
  ushort_t* B0l      = (ushort_t*)alloc(4 * 4 * 64 * 8 * 2);
  ushort_t* Bgh      = (ushort_t*)alloc(4 * 8 * 64 * 8 * 2);
  ushort_t* Bgl      = (ushort_t*)alloc(4 * 8 * 64 * 8 * 2);
  int*      gs       = (int*)alloc((size_t)(B + 1) * 4);
  float*    gvec     = (float*)alloc((size_t)B * 64 * 4);
  (void)ws_size; (void)n_in;

  // contention-free bucketed CSR build (fully parallel spine)
  k_ehist<<<NB_E, 256, 0, stream>>>(ei + E, bhistT, E, NBUK);
  k_btot<<<NBUK, 256, 0, stream>>>(bhistT, bcnt, NB_E);
  k_bscan<<<1, 512, 0, stream>>>(bcnt, edgebase, NBUK, rowstart, N, E);
  k_bbase<<<NBUK, 256, 0, stream>>>(bhistT, edgebase, NB_E);
  k_ebucket<<<NB_E, 256, 0, stream>>>(ei, ei + E, bhistT, bedges, E, NBUK);
  k_ebsort<<<NBUK, 256, 0, stream>>>(bedges, edgebase, bcnt, colidx, rowstart, dinv, N);
  // weight prep
  k_qpre<<<1, 256, 0, stream>>>(gat_w, att_s, att_d, q_src, q_dst);
  k_wswz0<<<4, 256, 0, stream>>>(w0, B0h, B0l);
  k_wswzg<<<8, 256, 0, stream>>>(gat_w, Bgh, Bgl);

  const int AGB = 2048;
  // K1: h0' = bf16(dinv * (x @ W0))  (MFMA)
  k_gemm0_mfma<<<1024, 256, 0, stream>>>(x, B0h, B0l, dinv, hbuf, N, NT);
  // K2: x1 = relu(dinv*agg(h0')+b0); h1' = bf16(dinv*(x1@W1))
  k_agg_gemm<<<AGB, 256, 0, stream>>>(hbuf, dinv, rowstart, colidx, b0, w1, hbuf2, N);
  // K3
  k_agg_gemm<<<AGB, 256, 0, stream>>>(hbuf2, dinv, rowstart, colidx, b1, w2, hbuf, N);
  // K4: x3 (bf16) + attention logits (fp32)
  k_agg_gatpre<<<AGB, 256, 0, stream>>>(hbuf, dinv, rowstart, colidx, b2,
                                        q_src, q_dst, xg, a_src, a_dst, N);
  // K5a: softmax-weighted gather in x-space -> bf16 hi/lo planes
  k_gat_gather<<<(N + 3) / 4, 256, 0, stream>>>(xg, a_src, a_dst, rowstart, colidx,
                                                Ahi, Alo, N);
  // K5b: projection via MFMA
  k_gat_proj_mfma<<<1024, 256, 0, stream>>>(Ahi, Alo, Bgh, Bgl, gat_b, gatout, N, NT);
  // pooling + head
  k_gstart<<<(B + 1 + 255) / 256, 256, 0, stream>>>(batch, gs, N, B);
  k_pool<<<(B + 3) / 4, 256, 0, stream>>>(gatout, gs, gvec, B);
  k_mlp<<<(B + 255) / 256, 256, 0, stream>>>(gvec, l1w, l1b, l2w, l2b, (float*)d_out, B);
}